// Round 1
// baseline (478.314 us; speedup 1.0000x reference)
//
#include <hip/hip_runtime.h>
#include <math.h>

// Problem constants (compile-time, from the reference):
//   B=256, T=2560, D=128, G=64 groups, sizes cycle 16/32/48/64.
//   Supergroup of 4 groups spans 160 rows; offsets within supergroup: 0,16,48,96.
constexpr int D = 128;
constexpr int B = 256;
constexpr int T = 2560;
constexpr int G = 64;

__global__ __launch_bounds__(256) void ragged_attn_kernel(
    const float* __restrict__ s_i,     // [B, D]
    const float* __restrict__ theta,   // [B, T, D]
    float* __restrict__ out)           // [B, G, D]
{
    const int g = blockIdx.x;
    const int b = blockIdx.y;

    const int gm = g & 3;                        // position in supergroup
    const int S  = 16 * (gm + 1);                // group size: 16/32/48/64
    const int t0 = (g >> 2) * 160 + (gm * (gm + 1) / 2) * 16;  // 0,16,48,96

    // 64 rows x 128 floats = 32 KB tile (max group)
    __shared__ float4 lds_tile4[64 * 32];
    __shared__ float  u_sh[64];
    __shared__ float  attn_sh[64];
    __shared__ float  partial[128];

    const int tid = threadIdx.x;
    const int c = tid & 31;    // float4 column within row (covers 128 floats)
    const int r = tid >> 5;    // row-within-pass, 0..7

    // Each thread's slice of s_i[b] (same columns every pass)
    const float4 s4 = ((const float4*)(s_i + (size_t)b * D))[c];

    const float4* theta4 = (const float4*)(theta + ((size_t)b * T + t0) * D);

    // ---- Phase A: stage tile to LDS + fused partial dot products ----
    const int passes = S >> 3;   // 8 rows per pass
    for (int p = 0; p < passes; ++p) {
        const int t = p * 8 + r;
        const float4 th = theta4[t * 32 + c];    // wave reads 1 KB contiguous
        lds_tile4[t * 32 + c] = th;
        float dot = th.x * s4.x + th.y * s4.y + th.z * s4.z + th.w * s4.w;
        // reduce across the 32 lanes sharing this row (xor masks stay in-half)
        #pragma unroll
        for (int m = 16; m >= 1; m >>= 1) dot += __shfl_xor(dot, m);
        if (c == 0) u_sh[t] = dot * (1.0f / 128.0f);   // module divides by d0
    }
    __syncthreads();

    // ---- Phase B: softmax over S elements (single wave) ----
    if (tid < 64) {
        const float v = (tid < S) ? u_sh[tid] : -INFINITY;
        float mx = v;
        #pragma unroll
        for (int m = 32; m >= 1; m >>= 1) mx = fmaxf(mx, __shfl_xor(mx, m));
        const float e = (tid < S) ? __expf(v - mx) : 0.0f;
        float sum = e;
        #pragma unroll
        for (int m = 32; m >= 1; m >>= 1) sum += __shfl_xor(sum, m);
        attn_sh[tid] = e / sum;
    }
    __syncthreads();

    // ---- Phase C: out[d] = sum_t attn[t] * tile[t][d] ----
    const float* tile = (const float*)lds_tile4;
    const int d    = tid & 127;
    const int half = tid >> 7;               // two halves of the row range
    const int half_rows = S >> 1;            // S is always even
    const int tstart = half * half_rows;
    float acc = 0.0f;
    for (int t = 0; t < half_rows; ++t) {
        const int tt = tstart + t;
        acc += attn_sh[tt] * tile[tt * 128 + d];   // 2-way bank alias: free
    }
    if (half == 1) partial[d] = acc;
    __syncthreads();
    if (half == 0) {
        out[((size_t)b * G + g) * D + d] = acc + partial[d];
    }
}

extern "C" void kernel_launch(void* const* d_in, const int* in_sizes, int n_in,
                              void* d_out, int out_size, void* d_ws, size_t ws_size,
                              hipStream_t stream) {
    const float* s_i   = (const float*)d_in[0];
    const float* theta = (const float*)d_in[1];
    float* out = (float*)d_out;

    dim3 grid(G, B);   // g fast → consecutive blocks read contiguous theta rows
    ragged_attn_kernel<<<grid, 256, 0, stream>>>(s_i, theta, out);
}

// Round 3
// 451.744 us; speedup vs baseline: 1.0588x; 1.0588x over previous
//
#include <hip/hip_runtime.h>
#include <math.h>

// B=256, T=2560, D=128, G=64 groups, sizes cycle 16/32/48/64.
// Supergroup of 4 groups spans 160 rows; offsets within supergroup: 0,16,48,96.
constexpr int D = 128;
constexpr int B = 256;
constexpr int T = 2560;
constexpr int G = 64;

// Flash-style: process each group in chunks of <=32 rows with online softmax.
// LDS ~17 KB -> 8 blocks/CU (wave-capped), vs 33 KB / 4 blocks before.
__global__ __launch_bounds__(256, 8) void ragged_attn_kernel(
    const float* __restrict__ s_i,     // [B, D]
    const float* __restrict__ theta,   // [B, T, D]
    float* __restrict__ out)           // [B, G, D]
{
    const int g = blockIdx.x;
    const int b = blockIdx.y;

    const int gm = g & 3;                        // position in supergroup
    const int S  = 16 * (gm + 1);                // group size: 16/32/48/64
    const int t0 = (g >> 2) * 160 + (gm * (gm + 1) / 2) * 16;  // 0,16,48,96

    __shared__ float4 lds_tile4[32 * 32];  // 32 rows x 128 floats = 16 KB
    __shared__ float  u_sh[32];
    __shared__ float  e_sh[64];
    __shared__ float  partial[128];
    __shared__ float  m_sh, l_sh, alpha_sh;

    const int tid = threadIdx.x;
    const int c = tid & 31;    // float4 column within row
    const int r = tid >> 5;    // row-within-pass, 0..7
    const int d    = tid & 127;
    const int half = tid >> 7;

    const float4 s4 = ((const float4*)(s_i + (size_t)b * D))[c];
    const float4* theta4 = (const float4*)(theta + ((size_t)b * T + t0) * D);
    const float* tile = (const float*)lds_tile4;

    if (tid == 0) { m_sh = -INFINITY; l_sh = 0.0f; }
    __syncthreads();

    float acc = 0.0f;

    for (int t_off = 0; t_off < S; t_off += 32) {
        const int cr = min(32, S - t_off);       // 16 or 32 rows this chunk
        const int passes = cr >> 3;              // 2 or 4

        // ---- load chunk to LDS + fused dot products (paired for MLP) ----
        for (int p = 0; p < passes; p += 2) {
            const int ta = p * 8 + r;
            const int tb = ta + 8;
            const float4 a0 = theta4[(size_t)(t_off + ta) * 32 + c];
            const float4 a1 = theta4[(size_t)(t_off + tb) * 32 + c];
            lds_tile4[ta * 32 + c] = a0;
            lds_tile4[tb * 32 + c] = a1;
            float d0v = a0.x * s4.x + a0.y * s4.y + a0.z * s4.z + a0.w * s4.w;
            float d1v = a1.x * s4.x + a1.y * s4.y + a1.z * s4.z + a1.w * s4.w;
            #pragma unroll
            for (int m = 16; m >= 1; m >>= 1) {
                d0v += __shfl_xor(d0v, m);
                d1v += __shfl_xor(d1v, m);
            }
            if (c == 0) {
                u_sh[ta] = d0v * (1.0f / 128.0f);
                u_sh[tb] = d1v * (1.0f / 128.0f);
            }
        }
        __syncthreads();

        // ---- online softmax update (single wave) ----
        if (tid < 64) {
            const float m_old = m_sh;
            const float v = (tid < cr) ? u_sh[tid] : -INFINITY;
            float cm = v;
            #pragma unroll
            for (int m = 32; m >= 1; m >>= 1) cm = fmaxf(cm, __shfl_xor(cm, m));
            const float m_new = fmaxf(m_old, cm);
            const float e = (tid < cr) ? __expf(v - m_new) : 0.0f;
            float sum = e;
            #pragma unroll
            for (int m = 32; m >= 1; m >>= 1) sum += __shfl_xor(sum, m);
            e_sh[tid] = e;
            if (tid == 0) {
                const float alpha = __expf(m_old - m_new);  // 0 on first chunk
                alpha_sh = alpha;
                l_sh = l_sh * alpha + sum;
                m_sh = m_new;
            }
        }
        __syncthreads();

        // ---- accumulate: acc = acc*alpha + sum_t e[t] * tile[t][d] ----
        const float alpha = alpha_sh;
        const int hr = cr >> 1;
        const int tstart = half * hr;
        float a = 0.0f;
        for (int j = 0; j < hr; ++j) {
            const int tt = tstart + j;
            a += e_sh[tt] * tile[tt * 128 + d];  // 2-way bank alias: free
        }
        acc = acc * alpha + a;
        __syncthreads();   // protect tile/e_sh/alpha_sh before next chunk
    }

    const float l = l_sh;
    if (half == 1) partial[d] = acc;
    __syncthreads();
    if (half == 0) {
        out[((size_t)b * G + g) * D + d] = (acc + partial[d]) / l;
    }
}

extern "C" void kernel_launch(void* const* d_in, const int* in_sizes, int n_in,
                              void* d_out, int out_size, void* d_ws, size_t ws_size,
                              hipStream_t stream) {
    const float* s_i   = (const float*)d_in[0];
    const float* theta = (const float*)d_in[1];
    float* out = (float*)d_out;

    dim3 grid(G, B);   // g fast -> consecutive blocks read contiguous theta rows
    ragged_attn_kernel<<<grid, 256, 0, stream>>>(s_i, theta, out);
}

// Round 4
// 448.121 us; speedup vs baseline: 1.0674x; 1.0081x over previous
//
#include <hip/hip_runtime.h>
#include <math.h>

// B=256, T=2560, D=128, G=64 groups, sizes cycle 16/32/48/64.
// Supergroup of 4 groups spans 160 rows; offsets within supergroup: 0,16,48,96.
constexpr int D = 128;
constexpr int B = 256;
constexpr int T = 2560;
constexpr int G = 64;
constexpr int R = 8;   // rows per chunk (per-wave)

// One wave per (b,g): barrier-free. Each wave stages R-row chunks into a
// wave-private LDS slice, fuses the s·theta dot with staging, keeps online
// softmax state in registers (uniform across lanes), prefetches chunk ch+1
// during the softmax/accumulate of chunk ch.
__global__ __launch_bounds__(256, 8) void ragged_attn_wave(
    const float* __restrict__ s_i,     // [B, D]
    const float* __restrict__ theta,   // [B, T, D]
    float* __restrict__ out)           // [B, G, D]
{
    const int w    = threadIdx.x >> 6;      // wave in block: 0..3
    const int lane = threadIdx.x & 63;
    const int q    = blockIdx.x & 15;       // supergroup index (contig 160-row slab)
    const int b    = blockIdx.x >> 4;
    const int g    = q * 4 + w;             // block covers one full supergroup
    const int gm   = g & 3;
    const int S    = 16 * (gm + 1);         // 16/32/48/64
    const int t0   = (g >> 2) * 160 + (gm * (gm + 1) / 2) * 16;

    __shared__ float tile[4][R * 128];      // 4 KB per wave, wave-private
    __shared__ float u_sh[4][R];

    const int h = lane >> 5;                // row parity within load pair
    const int c = lane & 31;                // float4 column

    const float4 s4 = ((const float4*)(s_i + (size_t)b * D))[c];
    const float4* theta4 = (const float4*)(theta + ((size_t)b * T + t0) * D);

    float m = -INFINITY, l = 0.0f;
    float acc0 = 0.0f, acc1 = 0.0f;
    const int nch = S >> 3;                 // 2/4/6/8 chunks

    // prologue: chunk 0 loads in flight
    float4 rb[4];
    #pragma unroll
    for (int k = 0; k < 4; ++k)
        rb[k] = theta4[(size_t)(2 * k + h) * 32 + c];

    for (int ch = 0; ch < nch; ++ch) {
        // stage chunk + fused partial dots
        float dt[4];
        #pragma unroll
        for (int k = 0; k < 4; ++k) {
            const float4 v = rb[k];
            ((float4*)&tile[w][(2 * k + h) * 128])[c] = v;
            dt[k] = v.x * s4.x + v.y * s4.y + v.z * s4.z + v.w * s4.w;
        }
        // prefetch next chunk (overlaps with softmax + accumulate below)
        if (ch + 1 < nch) {
            #pragma unroll
            for (int k = 0; k < 4; ++k)
                rb[k] = theta4[(size_t)((ch + 1) * R + 2 * k + h) * 32 + c];
        }
        // reduce dots across the 32 lanes sharing each row (masks stay in-half)
        #pragma unroll
        for (int k = 0; k < 4; ++k) {
            #pragma unroll
            for (int msk = 16; msk >= 1; msk >>= 1)
                dt[k] += __shfl_xor(dt[k], msk);
        }
        if (c == 0) {
            #pragma unroll
            for (int k = 0; k < 4; ++k)
                u_sh[w][2 * k + h] = dt[k] * (1.0f / 128.0f);
        }
        // same-wave DS ops are in-order; compiler inserts lgkmcnt waits
        float uu[R];
        float cm = -INFINITY;
        #pragma unroll
        for (int t = 0; t < R; ++t) {
            uu[t] = u_sh[w][t];             // LDS broadcast
            cm = fmaxf(cm, uu[t]);
        }
        const float m_new = fmaxf(m, cm);
        const float alpha = __expf(m - m_new);   // 0 on first chunk
        acc0 *= alpha;
        acc1 *= alpha;
        float se = 0.0f;
        #pragma unroll
        for (int t = 0; t < R; ++t) {
            const float e = __expf(uu[t] - m_new);  // uniform across lanes
            se += e;
            acc0 += e * tile[w][t * 128 + lane];        // 2-way alias: free
            acc1 += e * tile[w][t * 128 + 64 + lane];
        }
        l = l * alpha + se;
        m = m_new;
    }

    float* op = out + ((size_t)b * G + g) * D;
    const float inv_l = 1.0f / l;
    op[lane]      = acc0 * inv_l;           // two 256 B coalesced stores
    op[lane + 64] = acc1 * inv_l;
}

extern "C" void kernel_launch(void* const* d_in, const int* in_sizes, int n_in,
                              void* d_out, int out_size, void* d_ws, size_t ws_size,
                              hipStream_t stream) {
    const float* s_i   = (const float*)d_in[0];
    const float* theta = (const float*)d_in[1];
    float* out = (float*)d_out;

    // 4096 blocks x 256 threads = 16384 waves = B*G groups
    ragged_attn_wave<<<dim3(B * 16), 256, 0, stream>>>(s_i, theta, out);
}